// Round 16
// baseline (528.763 us; speedup 1.0000x reference)
//
#include <hip/hip_runtime.h>

#define Bsz 16384
#define Dd  1024
#define H0d 1024
#define H1d 512
#define Ee  8
#define Tt  2
#define CH  4096          // batch-row chunk; 4 chunks; h/eo chunks stay L3-resident

typedef short  s8_t  __attribute__((ext_vector_type(8)));
typedef float  fx4   __attribute__((ext_vector_type(4)));
typedef __bf16 bf8_t __attribute__((ext_vector_type(8)));

__device__ __forceinline__ ushort f2bf(float f) {
    uint u = __builtin_bit_cast(uint, f);
    uint r = u + 0x7fffu + ((u >> 16) & 1u);
    return (ushort)(r >> 16);
}
__device__ __forceinline__ float bf2f(ushort u) {
    uint x = ((uint)u) << 16;
    return __builtin_bit_cast(float, x);
}
__device__ __forceinline__ void gload16(const void* g, void* l) {
    __builtin_amdgcn_global_load_lds((const __attribute__((address_space(1))) uint*)g,
                                     (__attribute__((address_space(3))) uint*)l, 16, 0, 0);
}
__device__ __forceinline__ bf8_t ldbf8(const ushort* p) {
    s8_t v = *(const s8_t*)p;
    return __builtin_bit_cast(bf8_t, v);
}

// ---------- fp32 -> bf16 elementwise (8 elems/thread) ----------
__global__ __launch_bounds__(256) void cvt_bf16_vec(const float* __restrict__ X,
                                                    ushort* __restrict__ Y, int n8) {
    int i = blockIdx.x * 256 + threadIdx.x;
    if (i >= n8) return;
    const float4* p = (const float4*)X + (size_t)i * 2;
    float4 a = p[0], b = p[1];
    s8_t o;
    o[0] = (short)f2bf(a.x); o[1] = (short)f2bf(a.y); o[2] = (short)f2bf(a.z); o[3] = (short)f2bf(a.w);
    o[4] = (short)f2bf(b.x); o[5] = (short)f2bf(b.y); o[6] = (short)f2bf(b.z); o[7] = (short)f2bf(b.w);
    ((s8_t*)Y)[i] = o;
}

// ---------- [E][R][C] f32 -> [E][C][R] bf16 tiled transpose ----------
__global__ __launch_bounds__(256) void transpose_cvt(const float* __restrict__ W,
                                                     ushort* __restrict__ WT, int R, int Cc) {
    __shared__ float tile[32][33];
    int e = blockIdx.z;
    int r0 = blockIdx.x * 32, c0 = blockIdx.y * 32;
    const float* Wp = W  + (size_t)e * R * Cc;
    ushort*      Tp = WT + (size_t)e * R * Cc;
    int tx = threadIdx.x, ty = threadIdx.y;   // 32 x 8
    #pragma unroll
    for (int i = 0; i < 32; i += 8)
        tile[ty + i][tx] = Wp[(size_t)(r0 + ty + i) * Cc + c0 + tx];
    __syncthreads();
    #pragma unroll
    for (int i = 0; i < 32; i += 8)
        Tp[(size_t)(c0 + ty + i) * R + r0 + tx] = f2bf(tile[tx][ty + i]);
}

// ---------- Wg [T][D][E] f32 -> WgT [T*E][D] bf16 ----------
__global__ __launch_bounds__(256) void transpose_wg(const float* __restrict__ Wg,
                                                    ushort* __restrict__ WgT) {
    int i = blockIdx.x * 256 + threadIdx.x;       // 16384 total
    int d = i & 1023, r = i >> 10;                // r = t*8+e
    int t = r >> 3, e = r & 7;
    WgT[i] = f2bf(Wg[((size_t)t * 1024 + d) * 8 + e]);
}

// ---------- gates via MFMA: logits = Xb * WgT^T, softmax over e per t ----------
__global__ __launch_bounds__(256) void gates_mfma(const ushort* __restrict__ Xb,
                                                  const ushort* __restrict__ WgT,
                                                  const float* __restrict__ bg,
                                                  float* __restrict__ gts) {
    int wave = threadIdx.x >> 6, lane = threadIdx.x & 63;
    int base = blockIdx.x * 64 + wave * 16;
    int l15 = lane & 15, lhi = lane >> 4;
    fx4 acc0 = {}, acc1 = {};
    const ushort* xp = Xb  + (size_t)(base + l15) * Dd + lhi * 8;
    const ushort* wp = WgT + (size_t)l15 * Dd + lhi * 8;
    #pragma unroll
    for (int kt = 0; kt < 32; kt += 2) {
        bf8_t a0 = ldbf8(xp + kt * 32);
        bf8_t b0 = ldbf8(wp + kt * 32);
        bf8_t a1 = ldbf8(xp + kt * 32 + 32);
        bf8_t b1 = ldbf8(wp + kt * 32 + 32);
        acc0 = __builtin_amdgcn_mfma_f32_16x16x32_bf16(a0, b0, acc0, 0, 0, 0);
        acc1 = __builtin_amdgcn_mfma_f32_16x16x32_bf16(a1, b1, acc1, 0, 0, 0);
    }
    fx4 acc = acc0 + acc1;
    float bgv = bg[l15];
    int t = l15 >> 3, e = l15 & 7;
    #pragma unroll
    for (int r = 0; r < 4; ++r) {
        float v = acc[r] + bgv;
        float mx = v;
        mx = fmaxf(mx, __shfl_xor(mx, 1));
        mx = fmaxf(mx, __shfl_xor(mx, 2));
        mx = fmaxf(mx, __shfl_xor(mx, 4));
        float p = expf(v - mx);
        float s = p;
        s += __shfl_xor(s, 1); s += __shfl_xor(s, 2); s += __shfl_xor(s, 4);
        int row = base + lhi * 4 + r;
        gts[(size_t)t * Bsz * 8 + (size_t)row * 8 + e] = p / s;
    }
}

// ---------- L0: 256x256 MFMA GEMM, 16 waves (4x4), 64x64/wave, BK=64 dbuf ----------
// R10 schedule (measured best). Expert-batched via blockIdx.y; A stride aStride elems,
// C stride mrows*N per expert.
__global__ __launch_bounds__(1024, 4) void gemm256(
    const ushort* __restrict__ Abase, const ushort* __restrict__ BtBase,
    const float* __restrict__ biasBase, ushort* __restrict__ CBase,
    int N, int K, int nbn, size_t aStride, int mrows) {
    __shared__ ushort lds[65536];          // 128 KiB: A[2][256][64] @0, B[2][256][64] @64KB
    char* ldsc = (char*)lds;

    const int tid = threadIdx.x;
    const int wave = tid >> 6, lane = tid & 63;
    const int l15 = lane & 15, lhi = lane >> 4;
    const int wr = wave >> 2, wc = wave & 3;      // 4x4 wave grid, 64x64 per wave

    const int ey = blockIdx.y;
    const ushort* A    = Abase   + (size_t)ey * aStride;
    const ushort* Bt   = BtBase  + (size_t)ey * (size_t)N * K;
    const float*  bias = biasBase + (size_t)ey * N;
    ushort*       C    = CBase   + (size_t)ey * (size_t)mrows * N;

    // bijective XCD swizzle within the per-expert block slice (gridDim.x % 8 == 0)
    int nwg = gridDim.x, wg = blockIdx.x;
    int q = nwg >> 3;
    int swz = (wg & 7) * q + (wg >> 3);
    const int bm = (swz / nbn) * 256, bn = (swz % nbn) * 256;

    // Staging: each wave writes 1KB linearly (8 rows x 8 slots of 16B); lane l ->
    // row l>>3, phys slot l&7. Pre-swizzled source column: logical = (l&7)^(l>>3).
    const int srcslot = (lane & 7) ^ (lane >> 3);
    const ushort* aSrc = A  + (size_t)(bm + wave * 8 + (lane >> 3)) * K + srcslot * 8;
    const ushort* bSrc = Bt + (size_t)(bn + wave * 8 + (lane >> 3)) * K + srcslot * 8;
    // frag-read swizzled slots: phys = logical ^ (row&7), row&7 == l15&7
    const int sc0 = lhi ^ (l15 & 7);
    const int sc1 = (4 | lhi) ^ (l15 & 7);

    fx4 acc[4][4] = {};

    const int nK = K >> 6;

#define STAGE(KT, d)                                                                            \
    {                                                                                           \
        gload16(aSrc + (size_t)(KT)*64,                ldsc + ((d)*32768 + wave * 1024));       \
        gload16(aSrc + (size_t)128 * K + (size_t)(KT)*64,                                       \
                ldsc + ((d)*32768 + 16384 + wave * 1024));                                      \
        gload16(bSrc + (size_t)(KT)*64,                ldsc + (65536 + (d)*32768 + wave * 1024));\
        gload16(bSrc + (size_t)128 * K + (size_t)(KT)*64,                                       \
                ldsc + (65536 + (d)*32768 + 16384 + wave * 1024));                              \
    }

    STAGE(0, 0);
    __syncthreads();          // drain tile 0

    for (int kt = 0; kt < nK; ++kt) {
        const int cur = kt & 1;
        if (kt + 1 < nK) STAGE(kt + 1, cur ^ 1);
        bf8_t aF[4][2], bF[4][2];
        #pragma unroll
        for (int m = 0; m < 4; ++m) {
            int Rb = cur * 32768 + (wr * 64 + m * 16 + l15) * 128;
            aF[m][0] = ldbf8((const ushort*)(ldsc + Rb + sc0 * 16));
            aF[m][1] = ldbf8((const ushort*)(ldsc + Rb + sc1 * 16));
        }
        #pragma unroll
        for (int n = 0; n < 4; ++n) {
            int Rb = 65536 + cur * 32768 + (wc * 64 + n * 16 + l15) * 128;
            bF[n][0] = ldbf8((const ushort*)(ldsc + Rb + sc0 * 16));
            bF[n][1] = ldbf8((const ushort*)(ldsc + Rb + sc1 * 16));
        }
        #pragma unroll
        for (int m = 0; m < 4; ++m)
            #pragma unroll
            for (int n = 0; n < 4; ++n)
                #pragma unroll
                for (int kk = 0; kk < 2; ++kk)
                    acc[m][n] = __builtin_amdgcn_mfma_f32_16x16x32_bf16(
                        aF[m][kk], bF[n][kk], acc[m][n], 0, 0, 0);
        __syncthreads();
    }
#undef STAGE

    float bv[4];
    #pragma unroll
    for (int ni = 0; ni < 4; ++ni) bv[ni] = bias[bn + wc * 64 + ni * 16 + l15];
    #pragma unroll
    for (int mi = 0; mi < 4; ++mi) {
        #pragma unroll
        for (int rr = 0; rr < 4; ++rr) {
            int row = bm + wr * 64 + mi * 16 + lhi * 4 + rr;
            ushort* cp = C + (size_t)row * N + bn + wc * 64 + l15;
            #pragma unroll
            for (int ni = 0; ni < 4; ++ni) {
                float v = acc[mi][ni][rr] + bv[ni];
                v = fmaxf(v, 0.f);
                cp[ni * 16] = f2bf(v);
            }
        }
    }
}

// ---------- L1: 256x128 MFMA GEMM, 16 waves (4x4), 64x32/wave, BK=64 dbuf ----------
// Expert-batched like gemm256. LDS 96KB: A[2][256][64] @0, B[2][128][64] @64KB.
__global__ __launch_bounds__(1024, 4) void gemm256x128(
    const ushort* __restrict__ Abase, const ushort* __restrict__ BtBase,
    const float* __restrict__ biasBase, ushort* __restrict__ CBase,
    int N, int K, int nbn, size_t aStride, int mrows) {
    __shared__ ushort lds[49152];          // 96 KiB
    char* ldsc = (char*)lds;

    const int tid = threadIdx.x;
    const int wave = tid >> 6, lane = tid & 63;
    const int l15 = lane & 15, lhi = lane >> 4;
    const int wr = wave >> 2, wc = wave & 3;      // 4x4 wave grid, 64x32 per wave

    const int ey = blockIdx.y;
    const ushort* A    = Abase   + (size_t)ey * aStride;
    const ushort* Bt   = BtBase  + (size_t)ey * (size_t)N * K;
    const float*  bias = biasBase + (size_t)ey * N;
    ushort*       C    = CBase   + (size_t)ey * (size_t)mrows * N;

    int nwg = gridDim.x, wg = blockIdx.x;
    int q = nwg >> 3;
    int swz = (wg & 7) * q + (wg >> 3);
    const int bm = (swz / nbn) * 256, bn = (swz % nbn) * 128;

    const int srcslot = (lane & 7) ^ (lane >> 3);
    const ushort* aSrc = A  + (size_t)(bm + wave * 8 + (lane >> 3)) * K + srcslot * 8;
    const ushort* bSrc = Bt + (size_t)(bn + wave * 8 + (lane >> 3)) * K + srcslot * 8;
    const int sc0 = lhi ^ (l15 & 7);
    const int sc1 = (4 | lhi) ^ (l15 & 7);

    fx4 acc[4][2] = {};

    const int nK = K >> 6;

#define STAGE(KT, d)                                                                            \
    {                                                                                           \
        gload16(aSrc + (size_t)(KT)*64,                ldsc + ((d)*32768 + wave * 1024));       \
        gload16(aSrc + (size_t)128 * K + (size_t)(KT)*64,                                       \
                ldsc + ((d)*32768 + 16384 + wave * 1024));                                      \
        gload16(bSrc + (size_t)(KT)*64,                ldsc + (65536 + (d)*16384 + wave * 1024));\
    }

    STAGE(0, 0);
    __syncthreads();

    for (int kt = 0; kt < nK; ++kt) {
        const int cur = kt & 1;
        if (kt + 1 < nK) STAGE(kt + 1, cur ^ 1);
        bf8_t aF[4][2], bF[2][2];
        #pragma unroll
        for (int m = 0; m < 4; ++m) {
            int Rb = cur * 32768 + (wr * 64 + m * 16 + l15) * 128;
            aF[m][0] = ldbf8((const ushort*)(ldsc + Rb + sc0 * 16));
            aF[m][1] = ldbf8((const ushort*)(ldsc + Rb + sc1 * 16));
        }
        #pragma unroll
        for (int n = 0; n < 2; ++n) {
            int Rb = 65536 + cur * 16384 + (wc * 32 + n * 16 + l15) * 128;
            bF[n][0] = ldbf8((const ushort*)(ldsc + Rb + sc0 * 16));
            bF[n][1] = ldbf8((const ushort*)(ldsc + Rb + sc1 * 16));
        }
        #pragma unroll
        for (int m = 0; m < 4; ++m)
            #pragma unroll
            for (int n = 0; n < 2; ++n)
                #pragma unroll
                for (int kk = 0; kk < 2; ++kk)
                    acc[m][n] = __builtin_amdgcn_mfma_f32_16x16x32_bf16(
                        aF[m][kk], bF[n][kk], acc[m][n], 0, 0, 0);
        __syncthreads();
    }
#undef STAGE

    float bv[2];
    #pragma unroll
    for (int ni = 0; ni < 2; ++ni) bv[ni] = bias[bn + wc * 32 + ni * 16 + l15];
    #pragma unroll
    for (int mi = 0; mi < 4; ++mi) {
        #pragma unroll
        for (int rr = 0; rr < 4; ++rr) {
            int row = bm + wr * 64 + mi * 16 + lhi * 4 + rr;
            ushort* cp = C + (size_t)row * N + bn + wc * 32 + l15;
            #pragma unroll
            for (int ni = 0; ni < 2; ++ni) {
                float v = acc[mi][ni][rr] + bv[ni];
                v = fmaxf(v, 0.f);
                cp[ni * 16] = f2bf(v);
            }
        }
    }
}

// ---------- 128x128 MFMA GEMM fallback (MODE 1 RMW into fp32 out) ----------
template <int MODE>
__global__ __launch_bounds__(256, 2) void gemm_bt(
    const ushort* __restrict__ A, const ushort* __restrict__ Bt,
    const float* __restrict__ bias, ushort* __restrict__ C,
    float* __restrict__ outAcc, const float* __restrict__ gts,
    int expert, int N, int K, int nbn) {
    __shared__ ushort Ash[128 * 64];
    __shared__ ushort Bsh[128 * 64];
    const int tid = threadIdx.x;
    const int wave = tid >> 6, lane = tid & 63;

    int nwg = gridDim.x, wg = blockIdx.x;
    int q = nwg >> 3;
    int swz = (wg & 7) * q + (wg >> 3);
    const int bm = (swz / nbn) * 128, bn = (swz % nbn) * 128;

    const int wm = (wave >> 1) * 64, wn = (wave & 1) * 64;
    const int l15 = lane & 15, lhi = lane >> 4;

    fx4 acc[4][4] = {};

    const int nK = K >> 6;
    for (int kt = 0; kt < nK; ++kt) {
        __syncthreads();
        #pragma unroll
        for (int i = 0; i < 4; ++i) {
            int c = (wave * 4 + i) * 64 + lane;
            int row = c >> 3, g = c & 7;
            const ushort* ga = A + (size_t)(bm + row) * K + kt * 64 + g * 8;
            gload16(ga, (char*)Ash + (wave * 4 + i) * 1024);
            const ushort* gb = Bt + (size_t)(bn + row) * K + kt * 64 + g * 8;
            gload16(gb, (char*)Bsh + (wave * 4 + i) * 1024);
        }
        __syncthreads();
        #pragma unroll
        for (int kk = 0; kk < 2; ++kk) {
            bf8_t af[4], bf_[4];
            #pragma unroll
            for (int m = 0; m < 4; ++m)
                af[m] = ldbf8((const ushort*)((const char*)Ash + (wm + m * 16 + l15) * 128 + kk * 64 + lhi * 16));
            #pragma unroll
            for (int n = 0; n < 4; ++n)
                bf_[n] = ldbf8((const ushort*)((const char*)Bsh + (wn + n * 16 + l15) * 128 + kk * 64 + lhi * 16));
            #pragma unroll
            for (int m = 0; m < 4; ++m)
                #pragma unroll
                for (int n = 0; n < 4; ++n)
                    acc[m][n] = __builtin_amdgcn_mfma_f32_16x16x32_bf16(af[m], bf_[n], acc[m][n], 0, 0, 0);
        }
    }

    #pragma unroll
    for (int m = 0; m < 4; ++m) {
        #pragma unroll
        for (int r = 0; r < 4; ++r) {
            int row = bm + wm + m * 16 + lhi * 4 + r;
            if (MODE == 0) {
                ushort* cp = C + (size_t)row * N + bn + wn + l15;
                #pragma unroll
                for (int n = 0; n < 4; ++n) {
                    float v = acc[m][n][r] + bias[bn + wn + n * 16 + l15];
                    v = fmaxf(v, 0.f);
                    cp[n * 16] = f2bf(v);
                }
            } else {
                float g0 = gts[(size_t)row * 8 + expert];
                float g1 = gts[(size_t)Bsz * 8 + (size_t)row * 8 + expert];
                #pragma unroll
                for (int n = 0; n < 4; ++n) {
                    int col = bn + wn + n * 16 + l15;
                    float v = acc[m][n][r] + bias[col];
                    v = fmaxf(v, 0.f);
                    float* o0 = outAcc + (size_t)row * N + col;
                    float* o1 = outAcc + (size_t)Bsz * N + (size_t)row * N + col;
                    *o0 += g0 * v;
                    *o1 += g1 * v;
                }
            }
        }
    }
}

// ---------- combine (per chunk): out[t][cb+r][k] = sum_e g[t][cb+r][e] * eo[e][r][k] ----------
__global__ __launch_bounds__(256) void combine_kernel(const ushort* __restrict__ eo,
                                                      const float* __restrict__ gts,
                                                      float* __restrict__ out,
                                                      int chunkBase) {
    int wave = threadIdx.x >> 6, lane = threadIdx.x & 63;
    int b = blockIdx.x * 4 + wave;           // local row in [0, CH)
    int gb = chunkBase + b;                  // global row
    float g0[8], g1[8];
    #pragma unroll
    for (int e = 0; e < 8; ++e) {
        g0[e] = gts[(size_t)gb * 8 + e];
        g1[e] = gts[(size_t)Bsz * 8 + (size_t)gb * 8 + e];
    }
    int k0 = lane * 8;
    float a0[8], a1[8];
    #pragma unroll
    for (int j = 0; j < 8; ++j) { a0[j] = 0.f; a1[j] = 0.f; }
    #pragma unroll
    for (int e = 0; e < 8; ++e) {
        s8_t v = *(const s8_t*)(eo + ((size_t)e * CH + b) * H1d + k0);
        #pragma unroll
        for (int j = 0; j < 8; ++j) {
            float f = bf2f((ushort)v[j]);
            a0[j] += g0[e] * f;
            a1[j] += g1[e] * f;
        }
    }
    float4* o0 = (float4*)(out + (size_t)gb * H1d + k0);
    o0[0] = make_float4(a0[0], a0[1], a0[2], a0[3]);
    o0[1] = make_float4(a0[4], a0[5], a0[6], a0[7]);
    float4* o1 = (float4*)(out + (size_t)Bsz * H1d + (size_t)gb * H1d + k0);
    o1[0] = make_float4(a1[0], a1[1], a1[2], a1[3]);
    o1[1] = make_float4(a1[4], a1[5], a1[6], a1[7]);
}

extern "C" void kernel_launch(void* const* d_in, const int* in_sizes, int n_in,
                              void* d_out, int out_size, void* d_ws, size_t ws_size,
                              hipStream_t stream) {
    const float* X  = (const float*)d_in[0];
    const float* W0 = (const float*)d_in[1];
    const float* b0 = (const float*)d_in[2];
    const float* W1 = (const float*)d_in[3];
    const float* b1 = (const float*)d_in[4];
    const float* Wg = (const float*)d_in[5];
    const float* bg = (const float*)d_in[6];
    float* out = (float*)d_out;

    size_t off = 0;
    auto alloc = [&](size_t bytes) {
        char* p = (char*)d_ws + off;
        off += (bytes + 255) & ~(size_t)255;
        return (void*)p;
    };
    ushort* Xb  = (ushort*)alloc((size_t)Bsz * Dd * 2);
    ushort* W0T = (ushort*)alloc((size_t)Ee * Dd * H0d * 2);
    ushort* W1T = (ushort*)alloc((size_t)Ee * H0d * H1d * 2);
    float*  gts = (float*)alloc((size_t)Tt * Bsz * Ee * 4);
    ushort* WgT = (ushort*)alloc((size_t)Tt * Ee * Dd * 2);

    size_t h8Bytes = (size_t)Ee * CH * H0d * 2;   // 67 MB: h for all experts, one chunk
    size_t eoBytes = (size_t)Ee * CH * H1d * 2;   // 33.5 MB: eo, one chunk
    bool chunked = (off + h8Bytes + eoBytes + 512) <= ws_size;

    cvt_bf16_vec<<<(Bsz * Dd / 8 + 255) / 256, 256, 0, stream>>>(X, Xb, Bsz * Dd / 8);
    transpose_cvt<<<dim3(Dd / 32, H0d / 32, Ee), dim3(32, 8), 0, stream>>>(W0, W0T, Dd, H0d);
    transpose_cvt<<<dim3(H0d / 32, H1d / 32, Ee), dim3(32, 8), 0, stream>>>(W1, W1T, H0d, H1d);
    transpose_wg<<<(Tt * Ee * Dd) / 256, 256, 0, stream>>>(Wg, WgT);
    gates_mfma<<<Bsz / 64, 256, 0, stream>>>(Xb, WgT, bg, gts);

    if (chunked) {
        ushort* h8 = (ushort*)alloc(h8Bytes);
        ushort* eo = (ushort*)alloc(eoBytes);
        for (int c = 0; c < Bsz / CH; ++c) {
            const ushort* Xc = Xb + (size_t)c * CH * Dd;
            // L0: all 8 experts, grid (16*4, 8) = 512 blocks; h8[e][CH][H0d]
            gemm256<<<dim3((CH / 256) * (H0d / 256), Ee), 1024, 0, stream>>>(
                Xc, W0T, b0, h8, H0d, Dd, H0d / 256, 0, CH);
            // L1: all 8 experts, grid (16*4, 8) = 512 blocks; eo[e][CH][H1d]
            gemm256x128<<<dim3((CH / 256) * (H1d / 128), Ee), 1024, 0, stream>>>(
                h8, W1T, b1, eo, H1d, H0d, H1d / 128, (size_t)CH * H0d, CH);
            // combine this chunk (eo is L3-hot)
            combine_kernel<<<CH / 4, 256, 0, stream>>>(eo, gts, out, c * CH);
        }
    } else {
        // fallback: per-expert L0 + MODE1 RMW L1 (always fits: one h buffer)
        ushort* h1 = (ushort*)alloc((size_t)CH * H0d * 2 * (Bsz / CH)); // full-batch h
        hipMemsetAsync(d_out, 0, (size_t)out_size * sizeof(float), stream);
        for (int e = 0; e < Ee; ++e) {
            gemm256<<<dim3((Bsz / 256) * (H0d / 256), 1), 1024, 0, stream>>>(
                Xb, W0T + (size_t)e * Dd * H0d, b0 + (size_t)e * H0d, h1,
                H0d, Dd, H0d / 256, 0, Bsz);
            gemm_bt<1><<<dim3((Bsz / 128) * (H1d / 128)), 256, 0, stream>>>(
                h1, W1T + (size_t)e * H0d * H1d, b1 + (size_t)e * H1d,
                nullptr, out, gts, e, H1d, H0d, H1d / 128);
        }
    }
}

// Round 17
// 507.469 us; speedup vs baseline: 1.0420x; 1.0420x over previous
//
#include <hip/hip_runtime.h>

#define Bsz 16384
#define Dd  1024
#define H0d 1024
#define H1d 512
#define Ee  8
#define Tt  2

typedef short  s8_t  __attribute__((ext_vector_type(8)));
typedef float  fx4   __attribute__((ext_vector_type(4)));
typedef __bf16 bf8_t __attribute__((ext_vector_type(8)));

__device__ __forceinline__ ushort f2bf(float f) {
    uint u = __builtin_bit_cast(uint, f);
    uint r = u + 0x7fffu + ((u >> 16) & 1u);
    return (ushort)(r >> 16);
}
__device__ __forceinline__ float bf2f(ushort u) {
    uint x = ((uint)u) << 16;
    return __builtin_bit_cast(float, x);
}
__device__ __forceinline__ void gload16(const void* g, void* l) {
    __builtin_amdgcn_global_load_lds((const __attribute__((address_space(1))) uint*)g,
                                     (__attribute__((address_space(3))) uint*)l, 16, 0, 0);
}
__device__ __forceinline__ bf8_t ldbf8(const ushort* p) {
    s8_t v = *(const s8_t*)p;
    return __builtin_bit_cast(bf8_t, v);
}

// ---------- fp32 -> bf16 elementwise (8 elems/thread) ----------
__global__ __launch_bounds__(256) void cvt_bf16_vec(const float* __restrict__ X,
                                                    ushort* __restrict__ Y, int n8) {
    int i = blockIdx.x * 256 + threadIdx.x;
    if (i >= n8) return;
    const float4* p = (const float4*)X + (size_t)i * 2;
    float4 a = p[0], b = p[1];
    s8_t o;
    o[0] = (short)f2bf(a.x); o[1] = (short)f2bf(a.y); o[2] = (short)f2bf(a.z); o[3] = (short)f2bf(a.w);
    o[4] = (short)f2bf(b.x); o[5] = (short)f2bf(b.y); o[6] = (short)f2bf(b.z); o[7] = (short)f2bf(b.w);
    ((s8_t*)Y)[i] = o;
}

// ---------- [E][R][C] f32 -> [E][C][R] bf16 tiled transpose ----------
__global__ __launch_bounds__(256) void transpose_cvt(const float* __restrict__ W,
                                                     ushort* __restrict__ WT, int R, int Cc) {
    __shared__ float tile[32][33];
    int e = blockIdx.z;
    int r0 = blockIdx.x * 32, c0 = blockIdx.y * 32;
    const float* Wp = W  + (size_t)e * R * Cc;
    ushort*      Tp = WT + (size_t)e * R * Cc;
    int tx = threadIdx.x, ty = threadIdx.y;   // 32 x 8
    #pragma unroll
    for (int i = 0; i < 32; i += 8)
        tile[ty + i][tx] = Wp[(size_t)(r0 + ty + i) * Cc + c0 + tx];
    __syncthreads();
    #pragma unroll
    for (int i = 0; i < 32; i += 8)
        Tp[(size_t)(c0 + ty + i) * R + r0 + tx] = f2bf(tile[tx][ty + i]);
}

// ---------- Wg [T][D][E] f32 -> WgT [T*E][D] bf16 ----------
__global__ __launch_bounds__(256) void transpose_wg(const float* __restrict__ Wg,
                                                    ushort* __restrict__ WgT) {
    int i = blockIdx.x * 256 + threadIdx.x;       // 16384 total
    int d = i & 1023, r = i >> 10;                // r = t*8+e
    int t = r >> 3, e = r & 7;
    WgT[i] = f2bf(Wg[((size_t)t * 1024 + d) * 8 + e]);
}

// ---------- gates via MFMA: logits = Xb * WgT^T, softmax over e per t ----------
__global__ __launch_bounds__(256) void gates_mfma(const ushort* __restrict__ Xb,
                                                  const ushort* __restrict__ WgT,
                                                  const float* __restrict__ bg,
                                                  float* __restrict__ gts) {
    int wave = threadIdx.x >> 6, lane = threadIdx.x & 63;
    int base = blockIdx.x * 64 + wave * 16;
    int l15 = lane & 15, lhi = lane >> 4;
    fx4 acc0 = {}, acc1 = {};
    const ushort* xp = Xb  + (size_t)(base + l15) * Dd + lhi * 8;
    const ushort* wp = WgT + (size_t)l15 * Dd + lhi * 8;
    #pragma unroll
    for (int kt = 0; kt < 32; kt += 2) {
        bf8_t a0 = ldbf8(xp + kt * 32);
        bf8_t b0 = ldbf8(wp + kt * 32);
        bf8_t a1 = ldbf8(xp + kt * 32 + 32);
        bf8_t b1 = ldbf8(wp + kt * 32 + 32);
        acc0 = __builtin_amdgcn_mfma_f32_16x16x32_bf16(a0, b0, acc0, 0, 0, 0);
        acc1 = __builtin_amdgcn_mfma_f32_16x16x32_bf16(a1, b1, acc1, 0, 0, 0);
    }
    fx4 acc = acc0 + acc1;
    float bgv = bg[l15];
    int t = l15 >> 3, e = l15 & 7;
    #pragma unroll
    for (int r = 0; r < 4; ++r) {
        float v = acc[r] + bgv;
        float mx = v;
        mx = fmaxf(mx, __shfl_xor(mx, 1));
        mx = fmaxf(mx, __shfl_xor(mx, 2));
        mx = fmaxf(mx, __shfl_xor(mx, 4));
        float p = expf(v - mx);
        float s = p;
        s += __shfl_xor(s, 1); s += __shfl_xor(s, 2); s += __shfl_xor(s, 4);
        int row = base + lhi * 4 + r;
        gts[(size_t)t * Bsz * 8 + (size_t)row * 8 + e] = p / s;
    }
}

// ---------- L0: 256x256 MFMA GEMM, 16 waves (4x4), 64x64/wave, BK=64 dbuf ----------
// R10 schedule (measured best). Expert-batched: blockIdx.y selects expert within the
// group; A optionally per-expert (aStride elems), Bt/bias/C always per-expert.
__global__ __launch_bounds__(1024, 4) void gemm256(
    const ushort* __restrict__ Abase, const ushort* __restrict__ BtBase,
    const float* __restrict__ biasBase, ushort* __restrict__ CBase,
    int N, int K, int nbn, size_t aStride) {
    __shared__ ushort lds[65536];          // 128 KiB: A[2][256][64] @0, B[2][256][64] @64KB
    char* ldsc = (char*)lds;

    const int tid = threadIdx.x;
    const int wave = tid >> 6, lane = tid & 63;
    const int l15 = lane & 15, lhi = lane >> 4;
    const int wr = wave >> 2, wc = wave & 3;      // 4x4 wave grid, 64x64 per wave

    const int ey = blockIdx.y;
    const ushort* A    = Abase   + (size_t)ey * aStride;
    const ushort* Bt   = BtBase  + (size_t)ey * (size_t)N * K;
    const float*  bias = biasBase + (size_t)ey * N;
    ushort*       C    = CBase   + (size_t)ey * (size_t)Bsz * N;

    // bijective XCD swizzle within the per-expert 256-block slice (256 % 8 == 0)
    int nwg = gridDim.x, wg = blockIdx.x;
    int q = nwg >> 3;
    int swz = (wg & 7) * q + (wg >> 3);
    const int bm = (swz / nbn) * 256, bn = (swz % nbn) * 256;

    // Staging: each wave writes 1KB linearly (8 rows x 8 slots of 16B); lane l ->
    // row l>>3, phys slot l&7. Pre-swizzled source column: logical = (l&7)^(l>>3).
    const int srcslot = (lane & 7) ^ (lane >> 3);
    const ushort* aSrc = A  + (size_t)(bm + wave * 8 + (lane >> 3)) * K + srcslot * 8;
    const ushort* bSrc = Bt + (size_t)(bn + wave * 8 + (lane >> 3)) * K + srcslot * 8;
    // frag-read swizzled slots: phys = logical ^ (row&7), row&7 == l15&7
    const int sc0 = lhi ^ (l15 & 7);
    const int sc1 = (4 | lhi) ^ (l15 & 7);

    fx4 acc[4][4] = {};

    const int nK = K >> 6;

#define STAGE(KT, d)                                                                            \
    {                                                                                           \
        gload16(aSrc + (size_t)(KT)*64,                ldsc + ((d)*32768 + wave * 1024));       \
        gload16(aSrc + (size_t)128 * K + (size_t)(KT)*64,                                       \
                ldsc + ((d)*32768 + 16384 + wave * 1024));                                      \
        gload16(bSrc + (size_t)(KT)*64,                ldsc + (65536 + (d)*32768 + wave * 1024));\
        gload16(bSrc + (size_t)128 * K + (size_t)(KT)*64,                                       \
                ldsc + (65536 + (d)*32768 + 16384 + wave * 1024));                              \
    }

    STAGE(0, 0);
    __syncthreads();          // drain tile 0

    for (int kt = 0; kt < nK; ++kt) {
        const int cur = kt & 1;
        if (kt + 1 < nK) STAGE(kt + 1, cur ^ 1);
        bf8_t aF[4][2], bF[4][2];
        #pragma unroll
        for (int m = 0; m < 4; ++m) {
            int Rb = cur * 32768 + (wr * 64 + m * 16 + l15) * 128;
            aF[m][0] = ldbf8((const ushort*)(ldsc + Rb + sc0 * 16));
            aF[m][1] = ldbf8((const ushort*)(ldsc + Rb + sc1 * 16));
        }
        #pragma unroll
        for (int n = 0; n < 4; ++n) {
            int Rb = 65536 + cur * 32768 + (wc * 64 + n * 16 + l15) * 128;
            bF[n][0] = ldbf8((const ushort*)(ldsc + Rb + sc0 * 16));
            bF[n][1] = ldbf8((const ushort*)(ldsc + Rb + sc1 * 16));
        }
        #pragma unroll
        for (int m = 0; m < 4; ++m)
            #pragma unroll
            for (int n = 0; n < 4; ++n)
                #pragma unroll
                for (int kk = 0; kk < 2; ++kk)
                    acc[m][n] = __builtin_amdgcn_mfma_f32_16x16x32_bf16(
                        aF[m][kk], bF[n][kk], acc[m][n], 0, 0, 0);
        __syncthreads();
    }
#undef STAGE

    float bv[4];
    #pragma unroll
    for (int ni = 0; ni < 4; ++ni) bv[ni] = bias[bn + wc * 64 + ni * 16 + l15];
    #pragma unroll
    for (int mi = 0; mi < 4; ++mi) {
        #pragma unroll
        for (int rr = 0; rr < 4; ++rr) {
            int row = bm + wr * 64 + mi * 16 + lhi * 4 + rr;
            ushort* cp = C + (size_t)row * N + bn + wc * 64 + l15;
            #pragma unroll
            for (int ni = 0; ni < 4; ++ni) {
                float v = acc[mi][ni][rr] + bv[ni];
                v = fmaxf(v, 0.f);
                cp[ni * 16] = f2bf(v);
            }
        }
    }
}

// ---------- L1: 256x128 MFMA GEMM, 16 waves (4x4), 64x32/wave, BK=64 dbuf ----------
// Expert-batched like gemm256. LDS 96KB: A[2][256][64] @0, B[2][128][64] @64KB.
__global__ __launch_bounds__(1024, 4) void gemm256x128(
    const ushort* __restrict__ Abase, const ushort* __restrict__ BtBase,
    const float* __restrict__ biasBase, ushort* __restrict__ CBase,
    int N, int K, int nbn, size_t aStride) {
    __shared__ ushort lds[49152];          // 96 KiB
    char* ldsc = (char*)lds;

    const int tid = threadIdx.x;
    const int wave = tid >> 6, lane = tid & 63;
    const int l15 = lane & 15, lhi = lane >> 4;
    const int wr = wave >> 2, wc = wave & 3;      // 4x4 wave grid, 64x32 per wave

    const int ey = blockIdx.y;
    const ushort* A    = Abase   + (size_t)ey * aStride;
    const ushort* Bt   = BtBase  + (size_t)ey * (size_t)N * K;
    const float*  bias = biasBase + (size_t)ey * N;
    ushort*       C    = CBase   + (size_t)ey * (size_t)Bsz * N;

    int nwg = gridDim.x, wg = blockIdx.x;
    int q = nwg >> 3;
    int swz = (wg & 7) * q + (wg >> 3);
    const int bm = (swz / nbn) * 256, bn = (swz % nbn) * 128;

    const int srcslot = (lane & 7) ^ (lane >> 3);
    const ushort* aSrc = A  + (size_t)(bm + wave * 8 + (lane >> 3)) * K + srcslot * 8;
    const ushort* bSrc = Bt + (size_t)(bn + wave * 8 + (lane >> 3)) * K + srcslot * 8;
    const int sc0 = lhi ^ (l15 & 7);
    const int sc1 = (4 | lhi) ^ (l15 & 7);

    fx4 acc[4][2] = {};

    const int nK = K >> 6;

#define STAGE(KT, d)                                                                            \
    {                                                                                           \
        gload16(aSrc + (size_t)(KT)*64,                ldsc + ((d)*32768 + wave * 1024));       \
        gload16(aSrc + (size_t)128 * K + (size_t)(KT)*64,                                       \
                ldsc + ((d)*32768 + 16384 + wave * 1024));                                      \
        gload16(bSrc + (size_t)(KT)*64,                ldsc + (65536 + (d)*16384 + wave * 1024));\
    }

    STAGE(0, 0);
    __syncthreads();

    for (int kt = 0; kt < nK; ++kt) {
        const int cur = kt & 1;
        if (kt + 1 < nK) STAGE(kt + 1, cur ^ 1);
        bf8_t aF[4][2], bF[2][2];
        #pragma unroll
        for (int m = 0; m < 4; ++m) {
            int Rb = cur * 32768 + (wr * 64 + m * 16 + l15) * 128;
            aF[m][0] = ldbf8((const ushort*)(ldsc + Rb + sc0 * 16));
            aF[m][1] = ldbf8((const ushort*)(ldsc + Rb + sc1 * 16));
        }
        #pragma unroll
        for (int n = 0; n < 2; ++n) {
            int Rb = 65536 + cur * 16384 + (wc * 32 + n * 16 + l15) * 128;
            bF[n][0] = ldbf8((const ushort*)(ldsc + Rb + sc0 * 16));
            bF[n][1] = ldbf8((const ushort*)(ldsc + Rb + sc1 * 16));
        }
        #pragma unroll
        for (int m = 0; m < 4; ++m)
            #pragma unroll
            for (int n = 0; n < 2; ++n)
                #pragma unroll
                for (int kk = 0; kk < 2; ++kk)
                    acc[m][n] = __builtin_amdgcn_mfma_f32_16x16x32_bf16(
                        aF[m][kk], bF[n][kk], acc[m][n], 0, 0, 0);
        __syncthreads();
    }
#undef STAGE

    float bv[2];
    #pragma unroll
    for (int ni = 0; ni < 2; ++ni) bv[ni] = bias[bn + wc * 32 + ni * 16 + l15];
    #pragma unroll
    for (int mi = 0; mi < 4; ++mi) {
        #pragma unroll
        for (int rr = 0; rr < 4; ++rr) {
            int row = bm + wr * 64 + mi * 16 + lhi * 4 + rr;
            ushort* cp = C + (size_t)row * N + bn + wc * 32 + l15;
            #pragma unroll
            for (int ni = 0; ni < 2; ++ni) {
                float v = acc[mi][ni][rr] + bv[ni];
                v = fmaxf(v, 0.f);
                cp[ni * 16] = f2bf(v);
            }
        }
    }
}

// ---------- 128x128 MFMA GEMM fallback (MODE 1 RMW into fp32 out) ----------
template <int MODE>
__global__ __launch_bounds__(256, 2) void gemm_bt(
    const ushort* __restrict__ A, const ushort* __restrict__ Bt,
    const float* __restrict__ bias, ushort* __restrict__ C,
    float* __restrict__ outAcc, const float* __restrict__ gts,
    int expert, int N, int K, int nbn) {
    __shared__ ushort Ash[128 * 64];
    __shared__ ushort Bsh[128 * 64];
    const int tid = threadIdx.x;
    const int wave = tid >> 6, lane = tid & 63;

    int nwg = gridDim.x, wg = blockIdx.x;
    int q = nwg >> 3;
    int swz = (wg & 7) * q + (wg >> 3);
    const int bm = (swz / nbn) * 128, bn = (swz % nbn) * 128;

    const int wm = (wave >> 1) * 64, wn = (wave & 1) * 64;
    const int l15 = lane & 15, lhi = lane >> 4;

    fx4 acc[4][4] = {};

    const int nK = K >> 6;
    for (int kt = 0; kt < nK; ++kt) {
        __syncthreads();
        #pragma unroll
        for (int i = 0; i < 4; ++i) {
            int c = (wave * 4 + i) * 64 + lane;
            int row = c >> 3, g = c & 7;
            const ushort* ga = A + (size_t)(bm + row) * K + kt * 64 + g * 8;
            gload16(ga, (char*)Ash + (wave * 4 + i) * 1024);
            const ushort* gb = Bt + (size_t)(bn + row) * K + kt * 64 + g * 8;
            gload16(gb, (char*)Bsh + (wave * 4 + i) * 1024);
        }
        __syncthreads();
        #pragma unroll
        for (int kk = 0; kk < 2; ++kk) {
            bf8_t af[4], bf_[4];
            #pragma unroll
            for (int m = 0; m < 4; ++m)
                af[m] = ldbf8((const ushort*)((const char*)Ash + (wm + m * 16 + l15) * 128 + kk * 64 + lhi * 16));
            #pragma unroll
            for (int n = 0; n < 4; ++n)
                bf_[n] = ldbf8((const ushort*)((const char*)Bsh + (wn + n * 16 + l15) * 128 + kk * 64 + lhi * 16));
            #pragma unroll
            for (int m = 0; m < 4; ++m)
                #pragma unroll
                for (int n = 0; n < 4; ++n)
                    acc[m][n] = __builtin_amdgcn_mfma_f32_16x16x32_bf16(af[m], bf_[n], acc[m][n], 0, 0, 0);
        }
    }

    #pragma unroll
    for (int m = 0; m < 4; ++m) {
        #pragma unroll
        for (int r = 0; r < 4; ++r) {
            int row = bm + wm + m * 16 + lhi * 4 + r;
            if (MODE == 0) {
                ushort* cp = C + (size_t)row * N + bn + wn + l15;
                #pragma unroll
                for (int n = 0; n < 4; ++n) {
                    float v = acc[m][n][r] + bias[bn + wn + n * 16 + l15];
                    v = fmaxf(v, 0.f);
                    cp[n * 16] = f2bf(v);
                }
            } else {
                float g0 = gts[(size_t)row * 8 + expert];
                float g1 = gts[(size_t)Bsz * 8 + (size_t)row * 8 + expert];
                #pragma unroll
                for (int n = 0; n < 4; ++n) {
                    int col = bn + wn + n * 16 + l15;
                    float v = acc[m][n][r] + bias[col];
                    v = fmaxf(v, 0.f);
                    float* o0 = outAcc + (size_t)row * N + col;
                    float* o1 = outAcc + (size_t)Bsz * N + (size_t)row * N + col;
                    *o0 += g0 * v;
                    *o1 += g1 * v;
                }
            }
        }
    }
}

// ---------- combine: out[t][b][k] = sum_e g[t][b][e] * eo[e][b][k] ----------
__global__ __launch_bounds__(256) void combine_kernel(const ushort* __restrict__ eo,
                                                      const float* __restrict__ gts,
                                                      float* __restrict__ out) {
    int wave = threadIdx.x >> 6, lane = threadIdx.x & 63;
    int b = blockIdx.x * 4 + wave;
    float g0[8], g1[8];
    #pragma unroll
    for (int e = 0; e < 8; ++e) {
        g0[e] = gts[(size_t)b * 8 + e];
        g1[e] = gts[(size_t)Bsz * 8 + (size_t)b * 8 + e];
    }
    int k0 = lane * 8;
    float a0[8], a1[8];
    #pragma unroll
    for (int j = 0; j < 8; ++j) { a0[j] = 0.f; a1[j] = 0.f; }
    #pragma unroll
    for (int e = 0; e < 8; ++e) {
        s8_t v = *(const s8_t*)(eo + ((size_t)e * Bsz + b) * H1d + k0);
        #pragma unroll
        for (int j = 0; j < 8; ++j) {
            float f = bf2f((ushort)v[j]);
            a0[j] += g0[e] * f;
            a1[j] += g1[e] * f;
        }
    }
    float4* o0 = (float4*)(out + (size_t)b * H1d + k0);
    o0[0] = make_float4(a0[0], a0[1], a0[2], a0[3]);
    o0[1] = make_float4(a0[4], a0[5], a0[6], a0[7]);
    float4* o1 = (float4*)(out + (size_t)Bsz * H1d + (size_t)b * H1d + k0);
    o1[0] = make_float4(a1[0], a1[1], a1[2], a1[3]);
    o1[1] = make_float4(a1[4], a1[5], a1[6], a1[7]);
}

extern "C" void kernel_launch(void* const* d_in, const int* in_sizes, int n_in,
                              void* d_out, int out_size, void* d_ws, size_t ws_size,
                              hipStream_t stream) {
    const float* X  = (const float*)d_in[0];
    const float* W0 = (const float*)d_in[1];
    const float* b0 = (const float*)d_in[2];
    const float* W1 = (const float*)d_in[3];
    const float* b1 = (const float*)d_in[4];
    const float* Wg = (const float*)d_in[5];
    const float* bg = (const float*)d_in[6];
    float* out = (float*)d_out;

    size_t off = 0;
    auto alloc = [&](size_t bytes) {
        char* p = (char*)d_ws + off;
        off += (bytes + 255) & ~(size_t)255;
        return (void*)p;
    };
    ushort* Xb  = (ushort*)alloc((size_t)Bsz * Dd * 2);
    ushort* W0T = (ushort*)alloc((size_t)Ee * Dd * H0d * 2);
    ushort* W1T = (ushort*)alloc((size_t)Ee * H0d * H1d * 2);
    float*  gts = (float*)alloc((size_t)Tt * Bsz * Ee * 4);
    ushort* WgT = (ushort*)alloc((size_t)Tt * Ee * Dd * 2);
    size_t eoBytes = (size_t)Ee * Bsz * H1d * 2;
    size_t hBytes  = (size_t)Bsz * H0d * 2;
    bool use_eo = (off + eoBytes + hBytes + 512) <= ws_size;
    ushort* eo = use_eo ? (ushort*)alloc(eoBytes) : nullptr;
    // expert-group size: largest {8,4,2,1} whose h buffers fit the remaining ws
    int EB = 1;
    if (use_eo) {
        size_t rem = (ws_size > off) ? ws_size - off : 0;
        if (rem >= 8 * (hBytes + 256)) EB = 8;
        else if (rem >= 4 * (hBytes + 256)) EB = 4;
        else if (rem >= 2 * (hBytes + 256)) EB = 2;
    }
    ushort* hG = (ushort*)alloc((size_t)EB * hBytes);

    cvt_bf16_vec<<<(Bsz * Dd / 8 + 255) / 256, 256, 0, stream>>>(X, Xb, Bsz * Dd / 8);
    transpose_cvt<<<dim3(Dd / 32, H0d / 32, Ee), dim3(32, 8), 0, stream>>>(W0, W0T, Dd, H0d);
    transpose_cvt<<<dim3(H0d / 32, H1d / 32, Ee), dim3(32, 8), 0, stream>>>(W1, W1T, H0d, H1d);
    transpose_wg<<<(Tt * Ee * Dd) / 256, 256, 0, stream>>>(Wg, WgT);
    gates_mfma<<<Bsz / 64, 256, 0, stream>>>(Xb, WgT, bg, gts);
    if (!use_eo) hipMemsetAsync(d_out, 0, (size_t)out_size * sizeof(float), stream);

    if (use_eo) {
        for (int g = 0; g < Ee; g += EB) {
            // L0: grid (256 tiles, EB experts); A=Xb shared (aStride 0); C = hG[e]
            gemm256<<<dim3((Bsz / 256) * (H0d / 256), EB), 1024, 0, stream>>>(
                Xb, W0T + (size_t)g * Dd * H0d, b0 + (size_t)g * H0d, hG,
                H0d, Dd, H0d / 256, 0);
            // L1: A = hG[e] (aStride Bsz*H0d); C = eo[g+e]
            gemm256x128<<<dim3((Bsz / 256) * (H1d / 128), EB), 1024, 0, stream>>>(
                hG, W1T + (size_t)g * H0d * H1d, b1 + (size_t)g * H1d,
                eo + (size_t)g * Bsz * H1d, H1d, H0d, H1d / 128, (size_t)Bsz * H0d);
        }
        combine_kernel<<<Bsz / 4, 256, 0, stream>>>(eo, gts, out);
    } else {
        for (int e = 0; e < Ee; ++e) {
            gemm256<<<dim3((Bsz / 256) * (H0d / 256), 1), 1024, 0, stream>>>(
                Xb, W0T + (size_t)e * Dd * H0d, b0 + (size_t)e * H0d, hG,
                H0d, Dd, H0d / 256, 0);
            gemm_bt<1><<<dim3((Bsz / 128) * (H1d / 128)), 256, 0, stream>>>(
                hG, W1T + (size_t)e * H0d * H1d, b1 + (size_t)e * H1d,
                nullptr, out, gts, e, H1d, H0d, H1d / 128);
        }
    }
}

// Round 19
// 484.639 us; speedup vs baseline: 1.0910x; 1.0471x over previous
//
#include <hip/hip_runtime.h>

#define Bsz 16384
#define Dd  1024
#define H0d 1024
#define H1d 512
#define Ee  8
#define Tt  2

typedef short  s8_t  __attribute__((ext_vector_type(8)));
typedef float  fx4   __attribute__((ext_vector_type(4)));
typedef __bf16 bf8_t __attribute__((ext_vector_type(8)));

__device__ __forceinline__ ushort f2bf(float f) {
    uint u = __builtin_bit_cast(uint, f);
    uint r = u + 0x7fffu + ((u >> 16) & 1u);
    return (ushort)(r >> 16);
}
__device__ __forceinline__ float bf2f(ushort u) {
    uint x = ((uint)u) << 16;
    return __builtin_bit_cast(float, x);
}
__device__ __forceinline__ void gload16(const void* g, void* l) {
    __builtin_amdgcn_global_load_lds((const __attribute__((address_space(1))) uint*)g,
                                     (__attribute__((address_space(3))) uint*)l, 16, 0, 0);
}
__device__ __forceinline__ bf8_t ldbf8(const ushort* p) {
    s8_t v = *(const s8_t*)p;
    return __builtin_bit_cast(bf8_t, v);
}

// ---------- fp32 -> bf16 elementwise (8 elems/thread) ----------
__global__ __launch_bounds__(256) void cvt_bf16_vec(const float* __restrict__ X,
                                                    ushort* __restrict__ Y, int n8) {
    int i = blockIdx.x * 256 + threadIdx.x;
    if (i >= n8) return;
    const float4* p = (const float4*)X + (size_t)i * 2;
    float4 a = p[0], b = p[1];
    s8_t o;
    o[0] = (short)f2bf(a.x); o[1] = (short)f2bf(a.y); o[2] = (short)f2bf(a.z); o[3] = (short)f2bf(a.w);
    o[4] = (short)f2bf(b.x); o[5] = (short)f2bf(b.y); o[6] = (short)f2bf(b.z); o[7] = (short)f2bf(b.w);
    ((s8_t*)Y)[i] = o;
}

// ---------- [E][R][C] f32 -> [E][C][R] bf16 tiled transpose (vectorized) ----------
// block (8,32): float4 loads, ushort4 stores; 32x32 tile via LDS.
__global__ __launch_bounds__(256) void transpose_cvt(const float* __restrict__ W,
                                                     ushort* __restrict__ WT, int R, int Cc) {
    __shared__ float tile[32][33];
    int e = blockIdx.z;
    int r0 = blockIdx.x * 32, c0 = blockIdx.y * 32;
    const float* Wp = W  + (size_t)e * R * Cc;
    ushort*      Tp = WT + (size_t)e * R * Cc;
    int tx = threadIdx.x, ty = threadIdx.y;   // 8 x 32
    float4 v = *(const float4*)&Wp[(size_t)(r0 + ty) * Cc + c0 + tx * 4];
    tile[ty][tx * 4 + 0] = v.x; tile[ty][tx * 4 + 1] = v.y;
    tile[ty][tx * 4 + 2] = v.z; tile[ty][tx * 4 + 3] = v.w;
    __syncthreads();
    ushort4 o;
    o.x = f2bf(tile[tx * 4 + 0][ty]);
    o.y = f2bf(tile[tx * 4 + 1][ty]);
    o.z = f2bf(tile[tx * 4 + 2][ty]);
    o.w = f2bf(tile[tx * 4 + 3][ty]);
    *(ushort4*)&Tp[(size_t)(c0 + ty) * R + r0 + tx * 4] = o;
}

// ---------- Wg [T][D][E] f32 -> WgT [T*E][D] bf16 ----------
__global__ __launch_bounds__(256) void transpose_wg(const float* __restrict__ Wg,
                                                    ushort* __restrict__ WgT) {
    int i = blockIdx.x * 256 + threadIdx.x;       // 16384 total
    int d = i & 1023, r = i >> 10;                // r = t*8+e
    int t = r >> 3, e = r & 7;
    WgT[i] = f2bf(Wg[((size_t)t * 1024 + d) * 8 + e]);
}

// ---------- gates via MFMA: logits = Xb * WgT^T, softmax over e per t ----------
__global__ __launch_bounds__(256) void gates_mfma(const ushort* __restrict__ Xb,
                                                  const ushort* __restrict__ WgT,
                                                  const float* __restrict__ bg,
                                                  float* __restrict__ gts) {
    int wave = threadIdx.x >> 6, lane = threadIdx.x & 63;
    int base = blockIdx.x * 64 + wave * 16;
    int l15 = lane & 15, lhi = lane >> 4;
    fx4 acc0 = {}, acc1 = {};
    const ushort* xp = Xb  + (size_t)(base + l15) * Dd + lhi * 8;
    const ushort* wp = WgT + (size_t)l15 * Dd + lhi * 8;
    #pragma unroll
    for (int kt = 0; kt < 32; kt += 2) {
        bf8_t a0 = ldbf8(xp + kt * 32);
        bf8_t b0 = ldbf8(wp + kt * 32);
        bf8_t a1 = ldbf8(xp + kt * 32 + 32);
        bf8_t b1 = ldbf8(wp + kt * 32 + 32);
        acc0 = __builtin_amdgcn_mfma_f32_16x16x32_bf16(a0, b0, acc0, 0, 0, 0);
        acc1 = __builtin_amdgcn_mfma_f32_16x16x32_bf16(a1, b1, acc1, 0, 0, 0);
    }
    fx4 acc = acc0 + acc1;
    float bgv = bg[l15];
    int t = l15 >> 3, e = l15 & 7;
    #pragma unroll
    for (int r = 0; r < 4; ++r) {
        float v = acc[r] + bgv;
        float mx = v;
        mx = fmaxf(mx, __shfl_xor(mx, 1));
        mx = fmaxf(mx, __shfl_xor(mx, 2));
        mx = fmaxf(mx, __shfl_xor(mx, 4));
        float p = expf(v - mx);
        float s = p;
        s += __shfl_xor(s, 1); s += __shfl_xor(s, 2); s += __shfl_xor(s, 4);
        int row = base + lhi * 4 + r;
        gts[(size_t)t * Bsz * 8 + (size_t)row * 8 + e] = p / s;
    }
}

// ---------- 256x256 MFMA GEMM, 16 waves (4x4), 64x64/wave, BK=64 dbuf ----------
// R10 schedule (measured best). Used for BOTH layers (shape-generic: N=1024 or 512).
// Expert-batched: blockIdx.y selects expert; A stride aStride elems, Bt/bias/C per-expert.
__global__ __launch_bounds__(1024, 4) void gemm256(
    const ushort* __restrict__ Abase, const ushort* __restrict__ BtBase,
    const float* __restrict__ biasBase, ushort* __restrict__ CBase,
    int N, int K, int nbn, size_t aStride) {
    __shared__ ushort lds[65536];          // 128 KiB: A[2][256][64] @0, B[2][256][64] @64KB
    char* ldsc = (char*)lds;

    const int tid = threadIdx.x;
    const int wave = tid >> 6, lane = tid & 63;
    const int l15 = lane & 15, lhi = lane >> 4;
    const int wr = wave >> 2, wc = wave & 3;      // 4x4 wave grid, 64x64 per wave

    const int ey = blockIdx.y;
    const ushort* A    = Abase   + (size_t)ey * aStride;
    const ushort* Bt   = BtBase  + (size_t)ey * (size_t)N * K;
    const float*  bias = biasBase + (size_t)ey * N;
    ushort*       C    = CBase   + (size_t)ey * (size_t)Bsz * N;

    // bijective XCD swizzle within the per-expert block slice (gridDim.x % 8 == 0)
    int nwg = gridDim.x, wg = blockIdx.x;
    int q = nwg >> 3;
    int swz = (wg & 7) * q + (wg >> 3);
    const int bm = (swz / nbn) * 256, bn = (swz % nbn) * 256;

    // Staging: each wave writes 1KB linearly (8 rows x 8 slots of 16B); lane l ->
    // row l>>3, phys slot l&7. Pre-swizzled source column: logical = (l&7)^(l>>3).
    const int srcslot = (lane & 7) ^ (lane >> 3);
    const ushort* aSrc = A  + (size_t)(bm + wave * 8 + (lane >> 3)) * K + srcslot * 8;
    const ushort* bSrc = Bt + (size_t)(bn + wave * 8 + (lane >> 3)) * K + srcslot * 8;
    // frag-read swizzled slots: phys = logical ^ (row&7), row&7 == l15&7
    const int sc0 = lhi ^ (l15 & 7);
    const int sc1 = (4 | lhi) ^ (l15 & 7);

    fx4 acc[4][4] = {};

    const int nK = K >> 6;

#define STAGE(KT, d)                                                                            \
    {                                                                                           \
        gload16(aSrc + (size_t)(KT)*64,                ldsc + ((d)*32768 + wave * 1024));       \
        gload16(aSrc + (size_t)128 * K + (size_t)(KT)*64,                                       \
                ldsc + ((d)*32768 + 16384 + wave * 1024));                                      \
        gload16(bSrc + (size_t)(KT)*64,                ldsc + (65536 + (d)*32768 + wave * 1024));\
        gload16(bSrc + (size_t)128 * K + (size_t)(KT)*64,                                       \
                ldsc + (65536 + (d)*32768 + 16384 + wave * 1024));                              \
    }

    STAGE(0, 0);
    __syncthreads();          // drain tile 0

    for (int kt = 0; kt < nK; ++kt) {
        const int cur = kt & 1;
        if (kt + 1 < nK) STAGE(kt + 1, cur ^ 1);
        bf8_t aF[4][2], bF[4][2];
        #pragma unroll
        for (int m = 0; m < 4; ++m) {
            int Rb = cur * 32768 + (wr * 64 + m * 16 + l15) * 128;
            aF[m][0] = ldbf8((const ushort*)(ldsc + Rb + sc0 * 16));
            aF[m][1] = ldbf8((const ushort*)(ldsc + Rb + sc1 * 16));
        }
        #pragma unroll
        for (int n = 0; n < 4; ++n) {
            int Rb = 65536 + cur * 32768 + (wc * 64 + n * 16 + l15) * 128;
            bF[n][0] = ldbf8((const ushort*)(ldsc + Rb + sc0 * 16));
            bF[n][1] = ldbf8((const ushort*)(ldsc + Rb + sc1 * 16));
        }
        #pragma unroll
        for (int m = 0; m < 4; ++m)
            #pragma unroll
            for (int n = 0; n < 4; ++n)
                #pragma unroll
                for (int kk = 0; kk < 2; ++kk)
                    acc[m][n] = __builtin_amdgcn_mfma_f32_16x16x32_bf16(
                        aF[m][kk], bF[n][kk], acc[m][n], 0, 0, 0);
        __syncthreads();
    }
#undef STAGE

    float bv[4];
    #pragma unroll
    for (int ni = 0; ni < 4; ++ni) bv[ni] = bias[bn + wc * 64 + ni * 16 + l15];
    #pragma unroll
    for (int mi = 0; mi < 4; ++mi) {
        #pragma unroll
        for (int rr = 0; rr < 4; ++rr) {
            int row = bm + wr * 64 + mi * 16 + lhi * 4 + rr;
            ushort* cp = C + (size_t)row * N + bn + wc * 64 + l15;
            #pragma unroll
            for (int ni = 0; ni < 4; ++ni) {
                float v = acc[mi][ni][rr] + bv[ni];
                v = fmaxf(v, 0.f);
                cp[ni * 16] = f2bf(v);
            }
        }
    }
}

// ---------- 128x128 MFMA GEMM fallback (MODE 1 RMW into fp32 out) ----------
template <int MODE>
__global__ __launch_bounds__(256, 2) void gemm_bt(
    const ushort* __restrict__ A, const ushort* __restrict__ Bt,
    const float* __restrict__ bias, ushort* __restrict__ C,
    float* __restrict__ outAcc, const float* __restrict__ gts,
    int expert, int N, int K, int nbn) {
    __shared__ ushort Ash[128 * 64];
    __shared__ ushort Bsh[128 * 64];
    const int tid = threadIdx.x;
    const int wave = tid >> 6, lane = tid & 63;

    int nwg = gridDim.x, wg = blockIdx.x;
    int q = nwg >> 3;
    int swz = (wg & 7) * q + (wg >> 3);
    const int bm = (swz / nbn) * 128, bn = (swz % nbn) * 128;

    const int wm = (wave >> 1) * 64, wn = (wave & 1) * 64;
    const int l15 = lane & 15, lhi = lane >> 4;

    fx4 acc[4][4] = {};

    const int nK = K >> 6;
    for (int kt = 0; kt < nK; ++kt) {
        __syncthreads();
        #pragma unroll
        for (int i = 0; i < 4; ++i) {
            int c = (wave * 4 + i) * 64 + lane;
            int row = c >> 3, g = c & 7;
            const ushort* ga = A + (size_t)(bm + row) * K + kt * 64 + g * 8;
            gload16(ga, (char*)Ash + (wave * 4 + i) * 1024);
            const ushort* gb = Bt + (size_t)(bn + row) * K + kt * 64 + g * 8;
            gload16(gb, (char*)Bsh + (wave * 4 + i) * 1024);
        }
        __syncthreads();
        #pragma unroll
        for (int kk = 0; kk < 2; ++kk) {
            bf8_t af[4], bf_[4];
            #pragma unroll
            for (int m = 0; m < 4; ++m)
                af[m] = ldbf8((const ushort*)((const char*)Ash + (wm + m * 16 + l15) * 128 + kk * 64 + lhi * 16));
            #pragma unroll
            for (int n = 0; n < 4; ++n)
                bf_[n] = ldbf8((const ushort*)((const char*)Bsh + (wn + n * 16 + l15) * 128 + kk * 64 + lhi * 16));
            #pragma unroll
            for (int m = 0; m < 4; ++m)
                #pragma unroll
                for (int n = 0; n < 4; ++n)
                    acc[m][n] = __builtin_amdgcn_mfma_f32_16x16x32_bf16(af[m], bf_[n], acc[m][n], 0, 0, 0);
        }
    }

    #pragma unroll
    for (int m = 0; m < 4; ++m) {
        #pragma unroll
        for (int r = 0; r < 4; ++r) {
            int row = bm + wm + m * 16 + lhi * 4 + r;
            if (MODE == 0) {
                ushort* cp = C + (size_t)row * N + bn + wn + l15;
                #pragma unroll
                for (int n = 0; n < 4; ++n) {
                    float v = acc[m][n][r] + bias[bn + wn + n * 16 + l15];
                    v = fmaxf(v, 0.f);
                    cp[n * 16] = f2bf(v);
                }
            } else {
                float g0 = gts[(size_t)row * 8 + expert];
                float g1 = gts[(size_t)Bsz * 8 + (size_t)row * 8 + expert];
                #pragma unroll
                for (int n = 0; n < 4; ++n) {
                    int col = bn + wn + n * 16 + l15;
                    float v = acc[m][n][r] + bias[col];
                    v = fmaxf(v, 0.f);
                    float* o0 = outAcc + (size_t)row * N + col;
                    float* o1 = outAcc + (size_t)Bsz * N + (size_t)row * N + col;
                    *o0 += g0 * v;
                    *o1 += g1 * v;
                }
            }
        }
    }
}

// ---------- combine: out[t][b][k] = sum_e g[t][b][e] * eo[e][b][k] ----------
__global__ __launch_bounds__(256) void combine_kernel(const ushort* __restrict__ eo,
                                                      const float* __restrict__ gts,
                                                      float* __restrict__ out) {
    int wave = threadIdx.x >> 6, lane = threadIdx.x & 63;
    int b = blockIdx.x * 4 + wave;
    float g0[8], g1[8];
    #pragma unroll
    for (int e = 0; e < 8; ++e) {
        g0[e] = gts[(size_t)b * 8 + e];
        g1[e] = gts[(size_t)Bsz * 8 + (size_t)b * 8 + e];
    }
    int k0 = lane * 8;
    float a0[8], a1[8];
    #pragma unroll
    for (int j = 0; j < 8; ++j) { a0[j] = 0.f; a1[j] = 0.f; }
    #pragma unroll
    for (int e = 0; e < 8; ++e) {
        s8_t v = *(const s8_t*)(eo + ((size_t)e * Bsz + b) * H1d + k0);
        #pragma unroll
        for (int j = 0; j < 8; ++j) {
            float f = bf2f((ushort)v[j]);
            a0[j] += g0[e] * f;
            a1[j] += g1[e] * f;
        }
    }
    float4* o0 = (float4*)(out + (size_t)b * H1d + k0);
    o0[0] = make_float4(a0[0], a0[1], a0[2], a0[3]);
    o0[1] = make_float4(a0[4], a0[5], a0[6], a0[7]);
    float4* o1 = (float4*)(out + (size_t)Bsz * H1d + (size_t)b * H1d + k0);
    o1[0] = make_float4(a1[0], a1[1], a1[2], a1[3]);
    o1[1] = make_float4(a1[4], a1[5], a1[6], a1[7]);
}

extern "C" void kernel_launch(void* const* d_in, const int* in_sizes, int n_in,
                              void* d_out, int out_size, void* d_ws, size_t ws_size,
                              hipStream_t stream) {
    const float* X  = (const float*)d_in[0];
    const float* W0 = (const float*)d_in[1];
    const float* b0 = (const float*)d_in[2];
    const float* W1 = (const float*)d_in[3];
    const float* b1 = (const float*)d_in[4];
    const float* Wg = (const float*)d_in[5];
    const float* bg = (const float*)d_in[6];
    float* out = (float*)d_out;

    size_t off = 0;
    auto alloc = [&](size_t bytes) {
        char* p = (char*)d_ws + off;
        off += (bytes + 255) & ~(size_t)255;
        return (void*)p;
    };
    ushort* Xb  = (ushort*)alloc((size_t)Bsz * Dd * 2);
    ushort* W0T = (ushort*)alloc((size_t)Ee * Dd * H0d * 2);
    ushort* W1T = (ushort*)alloc((size_t)Ee * H0d * H1d * 2);
    float*  gts = (float*)alloc((size_t)Tt * Bsz * Ee * 4);
    ushort* WgT = (ushort*)alloc((size_t)Tt * Ee * Dd * 2);
    size_t eoBytes = (size_t)Ee * Bsz * H1d * 2;
    size_t hBytes  = (size_t)Bsz * H0d * 2;
    bool use_eo = (off + eoBytes + hBytes + 512) <= ws_size;
    ushort* eo = use_eo ? (ushort*)alloc(eoBytes) : nullptr;
    // expert-group size: largest {8,4,2,1} whose h buffers fit the remaining ws
    int EB = 1;
    if (use_eo) {
        size_t rem = (ws_size > off) ? ws_size - off : 0;
        if (rem >= 8 * (hBytes + 256)) EB = 8;
        else if (rem >= 4 * (hBytes + 256)) EB = 4;
        else if (rem >= 2 * (hBytes + 256)) EB = 2;
    }
    ushort* hG = (ushort*)alloc((size_t)EB * hBytes);

    cvt_bf16_vec<<<(Bsz * Dd / 8 + 255) / 256, 256, 0, stream>>>(X, Xb, Bsz * Dd / 8);
    transpose_cvt<<<dim3(Dd / 32, H0d / 32, Ee), dim3(8, 32), 0, stream>>>(W0, W0T, Dd, H0d);
    transpose_cvt<<<dim3(H0d / 32, H1d / 32, Ee), dim3(8, 32), 0, stream>>>(W1, W1T, H0d, H1d);
    transpose_wg<<<(Tt * Ee * Dd) / 256, 256, 0, stream>>>(Wg, WgT);
    gates_mfma<<<Bsz / 64, 256, 0, stream>>>(Xb, WgT, bg, gts);
    if (!use_eo) hipMemsetAsync(d_out, 0, (size_t)out_size * sizeof(float), stream);

    if (use_eo) {
        for (int g = 0; g < Ee; g += EB) {
            // L0: grid (256 tiles, EB experts); A=Xb shared (aStride 0); C = hG[e]
            gemm256<<<dim3((Bsz / 256) * (H0d / 256), EB), 1024, 0, stream>>>(
                Xb, W0T + (size_t)g * Dd * H0d, b0 + (size_t)g * H0d, hG,
                H0d, Dd, H0d / 256, 0);
            // L1: same 256x256 kernel at N=512; grid (128 tiles, EB); A = hG[e]
            gemm256<<<dim3((Bsz / 256) * (H1d / 256), EB), 1024, 0, stream>>>(
                hG, W1T + (size_t)g * H0d * H1d, b1 + (size_t)g * H1d,
                eo + (size_t)g * Bsz * H1d, H1d, H0d, H1d / 256, (size_t)Bsz * H0d);
        }
        combine_kernel<<<Bsz / 4, 256, 0, stream>>>(eo, gts, out);
    } else {
        for (int e = 0; e < Ee; ++e) {
            gemm256<<<dim3((Bsz / 256) * (H0d / 256), 1), 1024, 0, stream>>>(
                Xb, W0T + (size_t)e * Dd * H0d, b0 + (size_t)e * H0d, hG,
                H0d, Dd, H0d / 256, 0);
            gemm_bt<1><<<dim3((Bsz / 128) * (H1d / 128)), 256, 0, stream>>>(
                hG, W1T + (size_t)e * H0d * H1d, b1 + (size_t)e * H1d,
                nullptr, out, gts, e, H1d, H0d, H1d / 128);
        }
    }
}

// Round 23
// 484.424 us; speedup vs baseline: 1.0915x; 1.0004x over previous
//
#include <hip/hip_runtime.h>

#define Bsz 16384
#define Dd  1024
#define H0d 1024
#define H1d 512
#define Ee  8
#define Tt  2

typedef short  s8_t  __attribute__((ext_vector_type(8)));
typedef float  fx4   __attribute__((ext_vector_type(4)));
typedef __bf16 bf8_t __attribute__((ext_vector_type(8)));

__device__ __forceinline__ ushort f2bf(float f) {
    uint u = __builtin_bit_cast(uint, f);
    uint r = u + 0x7fffu + ((u >> 16) & 1u);
    return (ushort)(r >> 16);
}
__device__ __forceinline__ float bf2f(ushort u) {
    uint x = ((uint)u) << 16;
    return __builtin_bit_cast(float, x);
}
__device__ __forceinline__ void gload16(const void* g, void* l) {
    __builtin_amdgcn_global_load_lds((const __attribute__((address_space(1))) uint*)g,
                                     (__attribute__((address_space(3))) uint*)l, 16, 0, 0);
}
__device__ __forceinline__ bf8_t ldbf8(const ushort* p) {
    s8_t v = *(const s8_t*)p;
    return __builtin_bit_cast(bf8_t, v);
}

// ---------- fp32 -> bf16 elementwise (8 elems/thread) ----------
__global__ __launch_bounds__(256) void cvt_bf16_vec(const float* __restrict__ X,
                                                    ushort* __restrict__ Y, int n8) {
    int i = blockIdx.x * 256 + threadIdx.x;
    if (i >= n8) return;
    const float4* p = (const float4*)X + (size_t)i * 2;
    float4 a = p[0], b = p[1];
    s8_t o;
    o[0] = (short)f2bf(a.x); o[1] = (short)f2bf(a.y); o[2] = (short)f2bf(a.z); o[3] = (short)f2bf(a.w);
    o[4] = (short)f2bf(b.x); o[5] = (short)f2bf(b.y); o[6] = (short)f2bf(b.z); o[7] = (short)f2bf(b.w);
    ((s8_t*)Y)[i] = o;
}

// ---------- [E][R][C] f32 -> [E][C][R] bf16 tiled transpose (vectorized) ----------
// block (8,32): float4 loads, ushort4 stores; 32x32 tile via LDS.
__global__ __launch_bounds__(256) void transpose_cvt(const float* __restrict__ W,
                                                     ushort* __restrict__ WT, int R, int Cc) {
    __shared__ float tile[32][33];
    int e = blockIdx.z;
    int r0 = blockIdx.x * 32, c0 = blockIdx.y * 32;
    const float* Wp = W  + (size_t)e * R * Cc;
    ushort*      Tp = WT + (size_t)e * R * Cc;
    int tx = threadIdx.x, ty = threadIdx.y;   // 8 x 32
    float4 v = *(const float4*)&Wp[(size_t)(r0 + ty) * Cc + c0 + tx * 4];
    tile[ty][tx * 4 + 0] = v.x; tile[ty][tx * 4 + 1] = v.y;
    tile[ty][tx * 4 + 2] = v.z; tile[ty][tx * 4 + 3] = v.w;
    __syncthreads();
    ushort4 o;
    o.x = f2bf(tile[tx * 4 + 0][ty]);
    o.y = f2bf(tile[tx * 4 + 1][ty]);
    o.z = f2bf(tile[tx * 4 + 2][ty]);
    o.w = f2bf(tile[tx * 4 + 3][ty]);
    *(ushort4*)&Tp[(size_t)(c0 + ty) * R + r0 + tx * 4] = o;
}

// ---------- Wg [T][D][E] f32 -> WgT [T*E][D] bf16 ----------
__global__ __launch_bounds__(256) void transpose_wg(const float* __restrict__ Wg,
                                                    ushort* __restrict__ WgT) {
    int i = blockIdx.x * 256 + threadIdx.x;       // 16384 total
    int d = i & 1023, r = i >> 10;                // r = t*8+e
    int t = r >> 3, e = r & 7;
    WgT[i] = f2bf(Wg[((size_t)t * 1024 + d) * 8 + e]);
}

// ---------- gates via MFMA: logits = Xb * WgT^T, softmax over e per t ----------
__global__ __launch_bounds__(256) void gates_mfma(const ushort* __restrict__ Xb,
                                                  const ushort* __restrict__ WgT,
                                                  const float* __restrict__ bg,
                                                  float* __restrict__ gts) {
    int wave = threadIdx.x >> 6, lane = threadIdx.x & 63;
    int base = blockIdx.x * 64 + wave * 16;
    int l15 = lane & 15, lhi = lane >> 4;
    fx4 acc0 = {}, acc1 = {};
    const ushort* xp = Xb  + (size_t)(base + l15) * Dd + lhi * 8;
    const ushort* wp = WgT + (size_t)l15 * Dd + lhi * 8;
    #pragma unroll
    for (int kt = 0; kt < 32; kt += 2) {
        bf8_t a0 = ldbf8(xp + kt * 32);
        bf8_t b0 = ldbf8(wp + kt * 32);
        bf8_t a1 = ldbf8(xp + kt * 32 + 32);
        bf8_t b1 = ldbf8(wp + kt * 32 + 32);
        acc0 = __builtin_amdgcn_mfma_f32_16x16x32_bf16(a0, b0, acc0, 0, 0, 0);
        acc1 = __builtin_amdgcn_mfma_f32_16x16x32_bf16(a1, b1, acc1, 0, 0, 0);
    }
    fx4 acc = acc0 + acc1;
    float bgv = bg[l15];
    int t = l15 >> 3, e = l15 & 7;
    #pragma unroll
    for (int r = 0; r < 4; ++r) {
        float v = acc[r] + bgv;
        float mx = v;
        mx = fmaxf(mx, __shfl_xor(mx, 1));
        mx = fmaxf(mx, __shfl_xor(mx, 2));
        mx = fmaxf(mx, __shfl_xor(mx, 4));
        float p = expf(v - mx);
        float s = p;
        s += __shfl_xor(s, 1); s += __shfl_xor(s, 2); s += __shfl_xor(s, 4);
        int row = base + lhi * 4 + r;
        gts[(size_t)t * Bsz * 8 + (size_t)row * 8 + e] = p / s;
    }
}

// ---------- 256x256 MFMA GEMM, 16 waves (4x4), 64x64/wave, BK=64 dbuf ----------
// R10 schedule (measured best). Used for BOTH layers (shape-generic: N=1024 or 512).
// Expert-batched: blockIdx.y selects expert; A stride aStride elems, Bt/bias/C per-expert.
__global__ __launch_bounds__(1024, 4) void gemm256(
    const ushort* __restrict__ Abase, const ushort* __restrict__ BtBase,
    const float* __restrict__ biasBase, ushort* __restrict__ CBase,
    int N, int K, int nbn, size_t aStride) {
    __shared__ ushort lds[65536];          // 128 KiB: A[2][256][64] @0, B[2][256][64] @64KB
    char* ldsc = (char*)lds;

    const int tid = threadIdx.x;
    const int wave = tid >> 6, lane = tid & 63;
    const int l15 = lane & 15, lhi = lane >> 4;
    const int wr = wave >> 2, wc = wave & 3;      // 4x4 wave grid, 64x64 per wave

    const int ey = blockIdx.y;
    const ushort* A    = Abase   + (size_t)ey * aStride;
    const ushort* Bt   = BtBase  + (size_t)ey * (size_t)N * K;
    const float*  bias = biasBase + (size_t)ey * N;
    ushort*       C    = CBase   + (size_t)ey * (size_t)Bsz * N;

    // bijective XCD swizzle within the per-expert block slice (gridDim.x % 8 == 0)
    int nwg = gridDim.x, wg = blockIdx.x;
    int q = nwg >> 3;
    int swz = (wg & 7) * q + (wg >> 3);
    const int bm = (swz / nbn) * 256, bn = (swz % nbn) * 256;

    // Staging: each wave writes 1KB linearly (8 rows x 8 slots of 16B); lane l ->
    // row l>>3, phys slot l&7. Pre-swizzled source column: logical = (l&7)^(l>>3).
    const int srcslot = (lane & 7) ^ (lane >> 3);
    const ushort* aSrc = A  + (size_t)(bm + wave * 8 + (lane >> 3)) * K + srcslot * 8;
    const ushort* bSrc = Bt + (size_t)(bn + wave * 8 + (lane >> 3)) * K + srcslot * 8;
    // frag-read swizzled slots: phys = logical ^ (row&7), row&7 == l15&7
    const int sc0 = lhi ^ (l15 & 7);
    const int sc1 = (4 | lhi) ^ (l15 & 7);

    fx4 acc[4][4] = {};

    const int nK = K >> 6;

#define STAGE(KT, d)                                                                            \
    {                                                                                           \
        gload16(aSrc + (size_t)(KT)*64,                ldsc + ((d)*32768 + wave * 1024));       \
        gload16(aSrc + (size_t)128 * K + (size_t)(KT)*64,                                       \
                ldsc + ((d)*32768 + 16384 + wave * 1024));                                      \
        gload16(bSrc + (size_t)(KT)*64,                ldsc + (65536 + (d)*32768 + wave * 1024));\
        gload16(bSrc + (size_t)128 * K + (size_t)(KT)*64,                                       \
                ldsc + (65536 + (d)*32768 + 16384 + wave * 1024));                              \
    }

    STAGE(0, 0);
    __syncthreads();          // drain tile 0

    for (int kt = 0; kt < nK; ++kt) {
        const int cur = kt & 1;
        if (kt + 1 < nK) STAGE(kt + 1, cur ^ 1);
        bf8_t aF[4][2], bF[4][2];
        #pragma unroll
        for (int m = 0; m < 4; ++m) {
            int Rb = cur * 32768 + (wr * 64 + m * 16 + l15) * 128;
            aF[m][0] = ldbf8((const ushort*)(ldsc + Rb + sc0 * 16));
            aF[m][1] = ldbf8((const ushort*)(ldsc + Rb + sc1 * 16));
        }
        #pragma unroll
        for (int n = 0; n < 4; ++n) {
            int Rb = 65536 + cur * 32768 + (wc * 64 + n * 16 + l15) * 128;
            bF[n][0] = ldbf8((const ushort*)(ldsc + Rb + sc0 * 16));
            bF[n][1] = ldbf8((const ushort*)(ldsc + Rb + sc1 * 16));
        }
        #pragma unroll
        for (int m = 0; m < 4; ++m)
            #pragma unroll
            for (int n = 0; n < 4; ++n)
                #pragma unroll
                for (int kk = 0; kk < 2; ++kk)
                    acc[m][n] = __builtin_amdgcn_mfma_f32_16x16x32_bf16(
                        aF[m][kk], bF[n][kk], acc[m][n], 0, 0, 0);
        __syncthreads();
    }
#undef STAGE

    float bv[4];
    #pragma unroll
    for (int ni = 0; ni < 4; ++ni) bv[ni] = bias[bn + wc * 64 + ni * 16 + l15];
    #pragma unroll
    for (int mi = 0; mi < 4; ++mi) {
        #pragma unroll
        for (int rr = 0; rr < 4; ++rr) {
            int row = bm + wr * 64 + mi * 16 + lhi * 4 + rr;
            ushort* cp = C + (size_t)row * N + bn + wc * 64 + l15;
            #pragma unroll
            for (int ni = 0; ni < 4; ++ni) {
                float v = acc[mi][ni][rr] + bv[ni];
                v = fmaxf(v, 0.f);
                cp[ni * 16] = f2bf(v);
            }
        }
    }
}

// ---------- 128x128 MFMA GEMM fallback (MODE 1 RMW into fp32 out) ----------
template <int MODE>
__global__ __launch_bounds__(256, 2) void gemm_bt(
    const ushort* __restrict__ A, const ushort* __restrict__ Bt,
    const float* __restrict__ bias, ushort* __restrict__ C,
    float* __restrict__ outAcc, const float* __restrict__ gts,
    int expert, int N, int K, int nbn) {
    __shared__ ushort Ash[128 * 64];
    __shared__ ushort Bsh[128 * 64];
    const int tid = threadIdx.x;
    const int wave = tid >> 6, lane = tid & 63;

    int nwg = gridDim.x, wg = blockIdx.x;
    int q = nwg >> 3;
    int swz = (wg & 7) * q + (wg >> 3);
    const int bm = (swz / nbn) * 128, bn = (swz % nbn) * 128;

    const int wm = (wave >> 1) * 64, wn = (wave & 1) * 64;
    const int l15 = lane & 15, lhi = lane >> 4;

    fx4 acc[4][4] = {};

    const int nK = K >> 6;
    for (int kt = 0; kt < nK; ++kt) {
        __syncthreads();
        #pragma unroll
        for (int i = 0; i < 4; ++i) {
            int c = (wave * 4 + i) * 64 + lane;
            int row = c >> 3, g = c & 7;
            const ushort* ga = A + (size_t)(bm + row) * K + kt * 64 + g * 8;
            gload16(ga, (char*)Ash + (wave * 4 + i) * 1024);
            const ushort* gb = Bt + (size_t)(bn + row) * K + kt * 64 + g * 8;
            gload16(gb, (char*)Bsh + (wave * 4 + i) * 1024);
        }
        __syncthreads();
        #pragma unroll
        for (int kk = 0; kk < 2; ++kk) {
            bf8_t af[4], bf_[4];
            #pragma unroll
            for (int m = 0; m < 4; ++m)
                af[m] = ldbf8((const ushort*)((const char*)Ash + (wm + m * 16 + l15) * 128 + kk * 64 + lhi * 16));
            #pragma unroll
            for (int n = 0; n < 4; ++n)
                bf_[n] = ldbf8((const ushort*)((const char*)Bsh + (wn + n * 16 + l15) * 128 + kk * 64 + lhi * 16));
            #pragma unroll
            for (int m = 0; m < 4; ++m)
                #pragma unroll
                for (int n = 0; n < 4; ++n)
                    acc[m][n] = __builtin_amdgcn_mfma_f32_16x16x32_bf16(af[m], bf_[n], acc[m][n], 0, 0, 0);
        }
    }

    #pragma unroll
    for (int m = 0; m < 4; ++m) {
        #pragma unroll
        for (int r = 0; r < 4; ++r) {
            int row = bm + wm + m * 16 + lhi * 4 + r;
            if (MODE == 0) {
                ushort* cp = C + (size_t)row * N + bn + wn + l15;
                #pragma unroll
                for (int n = 0; n < 4; ++n) {
                    float v = acc[m][n][r] + bias[bn + wn + n * 16 + l15];
                    v = fmaxf(v, 0.f);
                    cp[n * 16] = f2bf(v);
                }
            } else {
                float g0 = gts[(size_t)row * 8 + expert];
                float g1 = gts[(size_t)Bsz * 8 + (size_t)row * 8 + expert];
                #pragma unroll
                for (int n = 0; n < 4; ++n) {
                    int col = bn + wn + n * 16 + l15;
                    float v = acc[m][n][r] + bias[col];
                    v = fmaxf(v, 0.f);
                    float* o0 = outAcc + (size_t)row * N + col;
                    float* o1 = outAcc + (size_t)Bsz * N + (size_t)row * N + col;
                    *o0 += g0 * v;
                    *o1 += g1 * v;
                }
            }
        }
    }
}

// ---------- combine: out[t][b][k] = sum_e g[t][b][e] * eo[e][b][k] ----------
__global__ __launch_bounds__(256) void combine_kernel(const ushort* __restrict__ eo,
                                                      const float* __restrict__ gts,
                                                      float* __restrict__ out) {
    int wave = threadIdx.x >> 6, lane = threadIdx.x & 63;
    int b = blockIdx.x * 4 + wave;
    float g0[8], g1[8];
    #pragma unroll
    for (int e = 0; e < 8; ++e) {
        g0[e] = gts[(size_t)b * 8 + e];
        g1[e] = gts[(size_t)Bsz * 8 + (size_t)b * 8 + e];
    }
    int k0 = lane * 8;
    float a0[8], a1[8];
    #pragma unroll
    for (int j = 0; j < 8; ++j) { a0[j] = 0.f; a1[j] = 0.f; }
    #pragma unroll
    for (int e = 0; e < 8; ++e) {
        s8_t v = *(const s8_t*)(eo + ((size_t)e * Bsz + b) * H1d + k0);
        #pragma unroll
        for (int j = 0; j < 8; ++j) {
            float f = bf2f((ushort)v[j]);
            a0[j] += g0[e] * f;
            a1[j] += g1[e] * f;
        }
    }
    float4* o0 = (float4*)(out + (size_t)b * H1d + k0);
    o0[0] = make_float4(a0[0], a0[1], a0[2], a0[3]);
    o0[1] = make_float4(a0[4], a0[5], a0[6], a0[7]);
    float4* o1 = (float4*)(out + (size_t)Bsz * H1d + (size_t)b * H1d + k0);
    o1[0] = make_float4(a1[0], a1[1], a1[2], a1[3]);
    o1[1] = make_float4(a1[4], a1[5], a1[6], a1[7]);
}

extern "C" void kernel_launch(void* const* d_in, const int* in_sizes, int n_in,
                              void* d_out, int out_size, void* d_ws, size_t ws_size,
                              hipStream_t stream) {
    const float* X  = (const float*)d_in[0];
    const float* W0 = (const float*)d_in[1];
    const float* b0 = (const float*)d_in[2];
    const float* W1 = (const float*)d_in[3];
    const float* b1 = (const float*)d_in[4];
    const float* Wg = (const float*)d_in[5];
    const float* bg = (const float*)d_in[6];
    float* out = (float*)d_out;

    size_t off = 0;
    auto alloc = [&](size_t bytes) {
        char* p = (char*)d_ws + off;
        off += (bytes + 255) & ~(size_t)255;
        return (void*)p;
    };
    ushort* Xb  = (ushort*)alloc((size_t)Bsz * Dd * 2);
    ushort* W0T = (ushort*)alloc((size_t)Ee * Dd * H0d * 2);
    ushort* W1T = (ushort*)alloc((size_t)Ee * H0d * H1d * 2);
    float*  gts = (float*)alloc((size_t)Tt * Bsz * Ee * 4);
    ushort* WgT = (ushort*)alloc((size_t)Tt * Ee * Dd * 2);
    size_t eoBytes = (size_t)Ee * Bsz * H1d * 2;
    size_t hBytes  = (size_t)Bsz * H0d * 2;
    bool use_eo = (off + eoBytes + hBytes + 512) <= ws_size;
    ushort* eo = use_eo ? (ushort*)alloc(eoBytes) : nullptr;
    // expert-group size: largest {8,4,2,1} whose h buffers fit the remaining ws
    int EB = 1;
    if (use_eo) {
        size_t rem = (ws_size > off) ? ws_size - off : 0;
        if (rem >= 8 * (hBytes + 256)) EB = 8;
        else if (rem >= 4 * (hBytes + 256)) EB = 4;
        else if (rem >= 2 * (hBytes + 256)) EB = 2;
    }
    ushort* hG = (ushort*)alloc((size_t)EB * hBytes);

    cvt_bf16_vec<<<(Bsz * Dd / 8 + 255) / 256, 256, 0, stream>>>(X, Xb, Bsz * Dd / 8);
    transpose_cvt<<<dim3(Dd / 32, H0d / 32, Ee), dim3(8, 32), 0, stream>>>(W0, W0T, Dd, H0d);
    transpose_cvt<<<dim3(H0d / 32, H1d / 32, Ee), dim3(8, 32), 0, stream>>>(W1, W1T, H0d, H1d);
    transpose_wg<<<(Tt * Ee * Dd) / 256, 256, 0, stream>>>(Wg, WgT);
    gates_mfma<<<Bsz / 64, 256, 0, stream>>>(Xb, WgT, bg, gts);
    if (!use_eo) hipMemsetAsync(d_out, 0, (size_t)out_size * sizeof(float), stream);

    if (use_eo) {
        for (int g = 0; g < Ee; g += EB) {
            // L0: grid (256 tiles, EB experts); A=Xb shared (aStride 0); C = hG[e]
            gemm256<<<dim3((Bsz / 256) * (H0d / 256), EB), 1024, 0, stream>>>(
                Xb, W0T + (size_t)g * Dd * H0d, b0 + (size_t)g * H0d, hG,
                H0d, Dd, H0d / 256, 0);
            // L1: same 256x256 kernel at N=512; grid (128 tiles, EB); A = hG[e]
            gemm256<<<dim3((Bsz / 256) * (H1d / 256), EB), 1024, 0, stream>>>(
                hG, W1T + (size_t)g * H0d * H1d, b1 + (size_t)g * H1d,
                eo + (size_t)g * Bsz * H1d, H1d, H0d, H1d / 256, (size_t)Bsz * H0d);
        }
        combine_kernel<<<Bsz / 4, 256, 0, stream>>>(eo, gts, out);
    } else {
        for (int e = 0; e < Ee; ++e) {
            gemm256<<<dim3((Bsz / 256) * (H0d / 256), 1), 1024, 0, stream>>>(
                Xb, W0T + (size_t)e * Dd * H0d, b0 + (size_t)e * H0d, hG,
                H0d, Dd, H0d / 256, 0);
            gemm_bt<1><<<dim3((Bsz / 128) * (H1d / 128)), 256, 0, stream>>>(
                hG, W1T + (size_t)e * H0d * H1d, b1 + (size_t)e * H1d,
                nullptr, out, gts, e, H1d, H0d, H1d / 128);
        }
    }
}